// Round 1
// baseline (6390.800 us; speedup 1.0000x reference)
//
#include <hip/hip_runtime.h>
#include <hip/hip_bf16.h>
#include <math.h>

#define D_MODEL 768
#define N_HEADS 12
#define D_HEAD  64
#define BATCH   2
#define SEQ     2048
#define ROWS    (BATCH*SEQ)          // 4096
#define D_FFN   (4*D_MODEL)          // 3072

// ---------------------------------------------------------------- LayerNorm
__global__ __launch_bounds__(256)
void ln_kernel(const float* __restrict__ x, const float* __restrict__ g,
               const float* __restrict__ beta, float* __restrict__ out) {
    int row = blockIdx.x;
    const float* xr = x + (size_t)row * D_MODEL;
    int t = threadIdx.x;
    float v0 = xr[t], v1 = xr[t + 256], v2 = xr[t + 512];
    float s  = v0 + v1 + v2;
    float s2 = v0*v0 + v1*v1 + v2*v2;
    __shared__ float rs[4], rs2[4];
    #pragma unroll
    for (int off = 32; off; off >>= 1) {
        s  += __shfl_down(s, off);
        s2 += __shfl_down(s2, off);
    }
    int wv = t >> 6, ln = t & 63;
    if (ln == 0) { rs[wv] = s; rs2[wv] = s2; }
    __syncthreads();
    float S  = rs[0] + rs[1] + rs[2] + rs[3];
    float S2 = rs2[0] + rs2[1] + rs2[2] + rs2[3];
    float mu  = S * (1.0f / D_MODEL);
    float var = S2 * (1.0f / D_MODEL) - mu * mu;
    float inv = rsqrtf(var + 1e-5f);
    float* orow = out + (size_t)row * D_MODEL;
    orow[t]       = (v0 - mu) * inv * g[t]       + beta[t];
    orow[t + 256] = (v1 - mu) * inv * g[t + 256] + beta[t + 256];
    orow[t + 512] = (v2 - mu) * inv * g[t + 512] + beta[t + 512];
}

// ---------------------------------------------------------------- fp32 GEMM
// C[M,N] = A[M,K] @ W[K,N] + bias (+res) (ACT==1 -> exact GELU)
// 128x128 tile, BK=16, 256 threads, 8x8 micro-tile per thread.
template<int ACT, bool RES>
__global__ __launch_bounds__(256)
void gemm_kernel(const float* __restrict__ A, const float* __restrict__ W,
                 const float* __restrict__ bias, const float* __restrict__ res,
                 float* __restrict__ C, int M, int N, int K) {
    __shared__ float As[16][132];
    __shared__ float Bs[16][132];
    int tid = threadIdx.x;
    int bm = blockIdx.y * 128, bn = blockIdx.x * 128;
    int tx = tid & 15, ty = tid >> 4;
    float acc[8][8] = {};
    for (int k0 = 0; k0 < K; k0 += 16) {
        #pragma unroll
        for (int r = 0; r < 2; ++r) {
            int idx = tid + 256 * r;
            int m = idx >> 2, c = idx & 3;
            float4 av = *reinterpret_cast<const float4*>(&A[(size_t)(bm + m) * K + k0 + 4 * c]);
            As[4*c+0][m] = av.x; As[4*c+1][m] = av.y;
            As[4*c+2][m] = av.z; As[4*c+3][m] = av.w;
            int kk = idx >> 5, nq = idx & 31;
            float4 bv = *reinterpret_cast<const float4*>(&W[(size_t)(k0 + kk) * N + bn + 4 * nq]);
            *reinterpret_cast<float4*>(&Bs[kk][4 * nq]) = bv;
        }
        __syncthreads();
        #pragma unroll
        for (int kk = 0; kk < 16; ++kk) {
            float a[8], b[8];
            #pragma unroll
            for (int i = 0; i < 8; ++i) a[i] = As[kk][8 * ty + i];
            #pragma unroll
            for (int j = 0; j < 8; ++j) b[j] = Bs[kk][8 * tx + j];
            #pragma unroll
            for (int i = 0; i < 8; ++i)
                #pragma unroll
                for (int j = 0; j < 8; ++j)
                    acc[i][j] += a[i] * b[j];
        }
        __syncthreads();
    }
    #pragma unroll
    for (int i = 0; i < 8; ++i) {
        size_t m = bm + 8 * ty + i;
        float vout[8];
        #pragma unroll
        for (int j = 0; j < 8; ++j) {
            int n = bn + 8 * tx + j;
            float v = acc[i][j] + bias[n];
            if (RES) v += res[m * N + n];
            if (ACT == 1) v = 0.5f * v * (1.0f + erff(v * 0.70710678118f));
            vout[j] = v;
        }
        *reinterpret_cast<float4*>(&C[m * N + bn + 8 * tx])     = make_float4(vout[0], vout[1], vout[2], vout[3]);
        *reinterpret_cast<float4*>(&C[m * N + bn + 8 * tx + 4]) = make_float4(vout[4], vout[5], vout[6], vout[7]);
    }
}

// ---------------------------------------------------------------- attention
// One block (256 threads) per (b, h, q-row). scores = (QK^T)*(qp kp^T)/64,
// causal, softmax, PV. Q/K/V stored [B*T, 768] (head h at col h*64).
__global__ __launch_bounds__(256)
void attn_kernel(const float* __restrict__ Q, const float* __restrict__ K,
                 const float* __restrict__ V, const float* __restrict__ qp,
                 const float* __restrict__ kp, float* __restrict__ ao) {
    int q  = blockIdx.x;
    int bh = blockIdx.y;            // b*12 + h
    int b  = bh / N_HEADS, h = bh % N_HEADS;
    __shared__ float qrow[64], qprow[64];
    __shared__ float s[SEQ];
    __shared__ float red[8];
    __shared__ float pv[4][64];
    int t = threadIdx.x;
    if (t < 64) {
        qrow[t]  = Q[((size_t)(b * SEQ + q)) * D_MODEL + h * 64 + t];
        qprow[t] = qp[((size_t)bh * SEQ + q) * 64 + t];
    }
    __syncthreads();
    float lmax = -1e30f;
    for (int k = t; k <= q; k += 256) {
        const float4* Kr  = reinterpret_cast<const float4*>(&K[((size_t)(b * SEQ + k)) * D_MODEL + h * 64]);
        const float4* kpr = reinterpret_cast<const float4*>(&kp[((size_t)bh * SEQ + k) * 64]);
        float sx = 0.f, sp = 0.f;
        #pragma unroll
        for (int d = 0; d < 16; ++d) {
            float4 kv = Kr[d], pk = kpr[d];
            float4 qv  = *reinterpret_cast<const float4*>(&qrow[4 * d]);
            float4 qpv = *reinterpret_cast<const float4*>(&qprow[4 * d]);
            sx += qv.x * kv.x + qv.y * kv.y + qv.z * kv.z + qv.w * kv.w;
            sp += qpv.x * pk.x + qpv.y * pk.y + qpv.z * pk.z + qpv.w * pk.w;
        }
        float val = sx * sp * (1.0f / 64.0f);
        s[k] = val;
        lmax = fmaxf(lmax, val);
    }
    #pragma unroll
    for (int off = 32; off; off >>= 1) lmax = fmaxf(lmax, __shfl_down(lmax, off));
    int wv = t >> 6, ln = t & 63;
    if (ln == 0) red[wv] = lmax;
    __syncthreads();
    float m = fmaxf(fmaxf(red[0], red[1]), fmaxf(red[2], red[3]));
    float lsum = 0.f;
    for (int k = t; k <= q; k += 256) {
        float p = __expf(s[k] - m);
        s[k] = p;
        lsum += p;
    }
    #pragma unroll
    for (int off = 32; off; off >>= 1) lsum += __shfl_down(lsum, off);
    if (ln == 0) red[4 + wv] = lsum;
    __syncthreads();
    float Z = red[4] + red[5] + red[6] + red[7];
    // PV: 4 groups of 64 lanes; lane = output dim d, group strides over k.
    int grp = t >> 6, d = t & 63;
    float acc = 0.f;
    for (int k = grp; k <= q; k += 4)
        acc += s[k] * V[((size_t)(b * SEQ + k)) * D_MODEL + h * 64 + d];
    pv[grp][d] = acc;
    __syncthreads();
    if (grp == 0) {
        float o = (pv[0][d] + pv[1][d] + pv[2][d] + pv[3][d]) / Z;
        ao[((size_t)(b * SEQ + q)) * D_MODEL + h * 64 + d] = o;
    }
}

// ---------------------------------------------------------------- launch
extern "C" void kernel_launch(void* const* d_in, const int* in_sizes, int n_in,
                              void* d_out, int out_size, void* d_ws, size_t ws_size,
                              hipStream_t stream) {
    const float* x     = (const float*)d_in[0];
    const float* q_pos = (const float*)d_in[1];
    const float* k_pos = (const float*)d_in[2];
    // d_in[3] = causal_mask (structural, unused)
    const float* Wq = (const float*)d_in[4];
    const float* bq = (const float*)d_in[5];
    const float* Wk = (const float*)d_in[6];
    const float* bk = (const float*)d_in[7];
    const float* Wv = (const float*)d_in[8];
    const float* bv = (const float*)d_in[9];
    const float* Wo = (const float*)d_in[10];
    const float* bo = (const float*)d_in[11];
    const float* ln1_g = (const float*)d_in[12];
    const float* ln1_b = (const float*)d_in[13];
    const float* ln2_g = (const float*)d_in[14];
    const float* ln2_b = (const float*)d_in[15];
    const float* W1 = (const float*)d_in[16];
    const float* b1 = (const float*)d_in[17];
    const float* W2 = (const float*)d_in[18];
    const float* b2 = (const float*)d_in[19];
    float* out = (float*)d_out;

    const size_t S = (size_t)ROWS * D_MODEL;   // 3145728 floats
    float* ws  = (float*)d_ws;
    float* h   = ws;          // LN1 out, reused as LN2 out
    float* Qm  = ws + S;
    float* Km  = ws + 2 * S;
    float* Vm  = ws + 3 * S;
    float* ao  = ws + 4 * S;
    float* x2  = ws + 5 * S;
    float* mid = ws + 6 * S;  // 4096 x 3072

    // LN1
    ln_kernel<<<ROWS, 256, 0, stream>>>(x, ln1_g, ln1_b, h);
    // QKV projections
    dim3 g768(D_MODEL / 128, ROWS / 128);
    gemm_kernel<0, false><<<g768, 256, 0, stream>>>(h, Wq, bq, nullptr, Qm, ROWS, D_MODEL, D_MODEL);
    gemm_kernel<0, false><<<g768, 256, 0, stream>>>(h, Wk, bk, nullptr, Km, ROWS, D_MODEL, D_MODEL);
    gemm_kernel<0, false><<<g768, 256, 0, stream>>>(h, Wv, bv, nullptr, Vm, ROWS, D_MODEL, D_MODEL);
    // attention
    attn_kernel<<<dim3(SEQ, BATCH * N_HEADS), 256, 0, stream>>>(Qm, Km, Vm, q_pos, k_pos, ao);
    // output projection + residual
    gemm_kernel<0, true><<<g768, 256, 0, stream>>>(ao, Wo, bo, x, x2, ROWS, D_MODEL, D_MODEL);
    // LN2
    ln_kernel<<<ROWS, 256, 0, stream>>>(x2, ln2_g, ln2_b, h);
    // FFN
    dim3 g3072(D_FFN / 128, ROWS / 128);
    gemm_kernel<1, false><<<g3072, 256, 0, stream>>>(h, W1, b1, nullptr, mid, ROWS, D_FFN, D_MODEL);
    gemm_kernel<0, true><<<g768, 256, 0, stream>>>(mid, W2, b2, x2, out, ROWS, D_MODEL, D_FFN);
}

// Round 2
// 1275.474 us; speedup vs baseline: 5.0105x; 5.0105x over previous
//
#include <hip/hip_runtime.h>
#include <hip/hip_bf16.h>
#include <math.h>

#define D_MODEL 768
#define N_HEADS 12
#define D_HEAD  64
#define BATCH   2
#define SEQ     2048
#define ROWS    (BATCH*SEQ)          // 4096
#define D_FFN   (4*D_MODEL)          // 3072

typedef short bf16x8 __attribute__((ext_vector_type(8)));
typedef float f32x4  __attribute__((ext_vector_type(4)));

__device__ __forceinline__ short f2bf(float f) {
    __hip_bfloat16 h = __float2bfloat16(f);
    return *reinterpret_cast<short*>(&h);
}

__device__ __forceinline__ bf16x8 load8_bf16(const float* __restrict__ p) {
    float4 a = *reinterpret_cast<const float4*>(p);
    float4 b = *reinterpret_cast<const float4*>(p + 4);
    bf16x8 r;
    r[0]=f2bf(a.x); r[1]=f2bf(a.y); r[2]=f2bf(a.z); r[3]=f2bf(a.w);
    r[4]=f2bf(b.x); r[5]=f2bf(b.y); r[6]=f2bf(b.z); r[7]=f2bf(b.w);
    return r;
}

// ---------------------------------------------------------------- LayerNorm
__global__ __launch_bounds__(256)
void ln_kernel(const float* __restrict__ x, const float* __restrict__ g,
               const float* __restrict__ beta, float* __restrict__ out) {
    int row = blockIdx.x;
    const float* xr = x + (size_t)row * D_MODEL;
    int t = threadIdx.x;
    float v0 = xr[t], v1 = xr[t + 256], v2 = xr[t + 512];
    float s  = v0 + v1 + v2;
    float s2 = v0*v0 + v1*v1 + v2*v2;
    __shared__ float rs[4], rs2[4];
    #pragma unroll
    for (int off = 32; off; off >>= 1) {
        s  += __shfl_down(s, off);
        s2 += __shfl_down(s2, off);
    }
    int wv = t >> 6, ln = t & 63;
    if (ln == 0) { rs[wv] = s; rs2[wv] = s2; }
    __syncthreads();
    float S  = rs[0] + rs[1] + rs[2] + rs[3];
    float S2 = rs2[0] + rs2[1] + rs2[2] + rs2[3];
    float mu  = S * (1.0f / D_MODEL);
    float var = S2 * (1.0f / D_MODEL) - mu * mu;
    float inv = rsqrtf(var + 1e-5f);
    float* orow = out + (size_t)row * D_MODEL;
    orow[t]       = (v0 - mu) * inv * g[t]       + beta[t];
    orow[t + 256] = (v1 - mu) * inv * g[t + 256] + beta[t + 256];
    orow[t + 512] = (v2 - mu) * inv * g[t + 512] + beta[t + 512];
}

// ---------------------------------------------------------------- fp32 GEMM
template<int ACT, bool RES>
__global__ __launch_bounds__(256)
void gemm_kernel(const float* __restrict__ A, const float* __restrict__ W,
                 const float* __restrict__ bias, const float* __restrict__ res,
                 float* __restrict__ C, int M, int N, int K) {
    __shared__ float As[16][132];
    __shared__ float Bs[16][132];
    int tid = threadIdx.x;
    int bm = blockIdx.y * 128, bn = blockIdx.x * 128;
    int tx = tid & 15, ty = tid >> 4;
    float acc[8][8] = {};
    for (int k0 = 0; k0 < K; k0 += 16) {
        #pragma unroll
        for (int r = 0; r < 2; ++r) {
            int idx = tid + 256 * r;
            int m = idx >> 2, c = idx & 3;
            float4 av = *reinterpret_cast<const float4*>(&A[(size_t)(bm + m) * K + k0 + 4 * c]);
            As[4*c+0][m] = av.x; As[4*c+1][m] = av.y;
            As[4*c+2][m] = av.z; As[4*c+3][m] = av.w;
            int kk = idx >> 5, nq = idx & 31;
            float4 bv = *reinterpret_cast<const float4*>(&W[(size_t)(k0 + kk) * N + bn + 4 * nq]);
            *reinterpret_cast<float4*>(&Bs[kk][4 * nq]) = bv;
        }
        __syncthreads();
        #pragma unroll
        for (int kk = 0; kk < 16; ++kk) {
            float a[8], b[8];
            #pragma unroll
            for (int i = 0; i < 8; ++i) a[i] = As[kk][8 * ty + i];
            #pragma unroll
            for (int j = 0; j < 8; ++j) b[j] = Bs[kk][8 * tx + j];
            #pragma unroll
            for (int i = 0; i < 8; ++i)
                #pragma unroll
                for (int j = 0; j < 8; ++j)
                    acc[i][j] += a[i] * b[j];
        }
        __syncthreads();
    }
    #pragma unroll
    for (int i = 0; i < 8; ++i) {
        size_t m = bm + 8 * ty + i;
        float vout[8];
        #pragma unroll
        for (int j = 0; j < 8; ++j) {
            int n = bn + 8 * tx + j;
            float v = acc[i][j] + bias[n];
            if (RES) v += res[m * N + n];
            if (ACT == 1) v = 0.5f * v * (1.0f + erff(v * 0.70710678118f));
            vout[j] = v;
        }
        *reinterpret_cast<float4*>(&C[m * N + bn + 8 * tx])     = make_float4(vout[0], vout[1], vout[2], vout[3]);
        *reinterpret_cast<float4*>(&C[m * N + bn + 8 * tx + 4]) = make_float4(vout[4], vout[5], vout[6], vout[7]);
    }
}

// ---------------------------------------------------------------- MFMA flash attention
// Block = 128 threads (2 waves). Each block handles TWO 32-row q-tiles
// (pairIdx and 63-pairIdx) -> exactly 33 K-tiles of 64 keys: uniform work.
// Wave w owns 16 q-rows. scores = (Q K^T)*(qp kp^T)/64, causal, online softmax.
__global__ __launch_bounds__(128)
void attn_mfma_kernel(const float* __restrict__ Q, const float* __restrict__ K,
                      const float* __restrict__ V, const float* __restrict__ qp,
                      const float* __restrict__ kp, float* __restrict__ ao) {
    int pairIdx = blockIdx.x;            // 0..31
    int bh = blockIdx.y;                 // b*12+h
    int b = bh / N_HEADS, h = bh % N_HEADS;
    __shared__ short Vt[64][72];         // V^T, padded stride
    __shared__ short Plds[2][16][72];    // per-wave P relayout buffer
    int tid  = threadIdx.x;
    int w    = tid >> 6, lane = tid & 63;
    int lr   = lane & 15;                // A-row / C-col index
    int lg   = lane >> 4;                // k-group 0..3

    #pragma unroll
    for (int phase = 0; phase < 2; ++phase) {
        int qt    = (phase == 0) ? pairIdx : 63 - pairIdx;  // 32-row tile idx
        int qbase = qt * 32 + w * 16;

        // Q / q_pos fragments (held in registers across all K-tiles)
        const float* Qrow  = Q  + ((size_t)(b * SEQ) + qbase + lr) * D_MODEL + h * 64;
        const float* qprow = qp + ((size_t)bh * SEQ + qbase + lr) * 64;
        bf16x8 qf0  = load8_bf16(Qrow  + lg * 8);
        bf16x8 qf1  = load8_bf16(Qrow  + 32 + lg * 8);
        bf16x8 qpf0 = load8_bf16(qprow + lg * 8);
        bf16x8 qpf1 = load8_bf16(qprow + 32 + lg * 8);

        f32x4 o_acc[4] = {};
        float m_run[4], l_run[4];
        #pragma unroll
        for (int r = 0; r < 4; ++r) { m_run[r] = -1e30f; l_run[r] = 0.f; }

        int nkt = qt / 2 + 1;
        for (int kt = 0; kt < nkt; ++kt) {
            __syncthreads();   // protect Vt reads of previous iteration
            {   // stage V^T (both waves cooperate; conflict-free 2B writes)
                int row = tid & 63, cb = (tid >> 6) * 32;
                const float* vr = V + ((size_t)(b * SEQ) + kt * 64 + row) * D_MODEL + h * 64 + cb;
                #pragma unroll
                for (int c = 0; c < 8; ++c) {
                    float4 v4 = *reinterpret_cast<const float4*>(vr + 4 * c);
                    Vt[cb + 4*c + 0][row] = f2bf(v4.x);
                    Vt[cb + 4*c + 1][row] = f2bf(v4.y);
                    Vt[cb + 4*c + 2][row] = f2bf(v4.z);
                    Vt[cb + 4*c + 3][row] = f2bf(v4.w);
                }
            }
            __syncthreads();

            // ---- scores: S_X and S_P over 4 kj-subtiles
            f32x4 sx[4] = {}, sp[4] = {};
            const float* Kbase  = K  + ((size_t)(b * SEQ) + kt * 64) * D_MODEL + h * 64;
            const float* kpbase = kp + ((size_t)bh * SEQ + kt * 64) * 64;
            #pragma unroll
            for (int sub = 0; sub < 4; ++sub) {
                const float* kr  = Kbase  + (size_t)(sub * 16 + lr) * D_MODEL;
                const float* kpr = kpbase + (size_t)(sub * 16 + lr) * 64;
                bf16x8 kf0 = load8_bf16(kr  + lg * 8);
                bf16x8 kf1 = load8_bf16(kr  + 32 + lg * 8);
                bf16x8 kq0 = load8_bf16(kpr + lg * 8);
                bf16x8 kq1 = load8_bf16(kpr + 32 + lg * 8);
                sx[sub] = __builtin_amdgcn_mfma_f32_16x16x32_bf16(qf0,  kf0, sx[sub], 0, 0, 0);
                sx[sub] = __builtin_amdgcn_mfma_f32_16x16x32_bf16(qf1,  kf1, sx[sub], 0, 0, 0);
                sp[sub] = __builtin_amdgcn_mfma_f32_16x16x32_bf16(qpf0, kq0, sp[sub], 0, 0, 0);
                sp[sub] = __builtin_amdgcn_mfma_f32_16x16x32_bf16(qpf1, kq1, sp[sub], 0, 0, 0);
            }

            // ---- combine, mask, online softmax (rows live in 16-lane groups)
            float sc[4][4];
            float pmax[4];
            #pragma unroll
            for (int r = 0; r < 4; ++r) {
                int row = qbase + lg * 4 + r;
                float mx = -1e30f;
                #pragma unroll
                for (int sub = 0; sub < 4; ++sub) {
                    int col = kt * 64 + sub * 16 + lr;
                    float v = sx[sub][r] * sp[sub][r] * (1.0f / 64.0f);
                    if (col > row) v = -1e30f;
                    sc[sub][r] = v;
                    mx = fmaxf(mx, v);
                }
                pmax[r] = mx;
            }
            #pragma unroll
            for (int off = 1; off < 16; off <<= 1)
                #pragma unroll
                for (int r = 0; r < 4; ++r)
                    pmax[r] = fmaxf(pmax[r], __shfl_xor(pmax[r], off));

            float psum[4];
            #pragma unroll
            for (int r = 0; r < 4; ++r) {
                float m_new = fmaxf(m_run[r], pmax[r]);
                float scale = __expf(m_run[r] - m_new);
                m_run[r] = m_new;
                float s = 0.f;
                #pragma unroll
                for (int sub = 0; sub < 4; ++sub) {
                    float p = __expf(sc[sub][r] - m_new);
                    sc[sub][r] = p;
                    s += p;
                }
                psum[r] = s;
                l_run[r] *= scale;
                #pragma unroll
                for (int ds = 0; ds < 4; ++ds) o_acc[ds][r] *= scale;
            }
            #pragma unroll
            for (int off = 1; off < 16; off <<= 1)
                #pragma unroll
                for (int r = 0; r < 4; ++r)
                    psum[r] += __shfl_xor(psum[r], off);
            #pragma unroll
            for (int r = 0; r < 4; ++r) l_run[r] += psum[r];

            // ---- P -> bf16 -> LDS (per-wave), read back as A-frags
            #pragma unroll
            for (int sub = 0; sub < 4; ++sub)
                #pragma unroll
                for (int r = 0; r < 4; ++r)
                    Plds[w][lg * 4 + r][sub * 16 + lr] = f2bf(sc[sub][r]);

            bf16x8 pa0 = *reinterpret_cast<bf16x8*>(&Plds[w][lr][lg * 8]);
            bf16x8 pa1 = *reinterpret_cast<bf16x8*>(&Plds[w][lr][32 + lg * 8]);

            // ---- PV
            #pragma unroll
            for (int ds = 0; ds < 4; ++ds) {
                bf16x8 vb0 = *reinterpret_cast<bf16x8*>(&Vt[ds * 16 + lr][lg * 8]);
                bf16x8 vb1 = *reinterpret_cast<bf16x8*>(&Vt[ds * 16 + lr][32 + lg * 8]);
                o_acc[ds] = __builtin_amdgcn_mfma_f32_16x16x32_bf16(pa0, vb0, o_acc[ds], 0, 0, 0);
                o_acc[ds] = __builtin_amdgcn_mfma_f32_16x16x32_bf16(pa1, vb1, o_acc[ds], 0, 0, 0);
            }
        }

        // ---- write O
        #pragma unroll
        for (int ds = 0; ds < 4; ++ds)
            #pragma unroll
            for (int r = 0; r < 4; ++r) {
                int row = qbase + lg * 4 + r;
                float val = o_acc[ds][r] / l_run[r];
                ao[((size_t)(b * SEQ) + row) * D_MODEL + h * 64 + ds * 16 + lr] = val;
            }
        __syncthreads();   // phases share Vt/Plds
    }
}

// ---------------------------------------------------------------- launch
extern "C" void kernel_launch(void* const* d_in, const int* in_sizes, int n_in,
                              void* d_out, int out_size, void* d_ws, size_t ws_size,
                              hipStream_t stream) {
    const float* x     = (const float*)d_in[0];
    const float* q_pos = (const float*)d_in[1];
    const float* k_pos = (const float*)d_in[2];
    // d_in[3] = causal_mask (structural, unused)
    const float* Wq = (const float*)d_in[4];
    const float* bq = (const float*)d_in[5];
    const float* Wk = (const float*)d_in[6];
    const float* bk = (const float*)d_in[7];
    const float* Wv = (const float*)d_in[8];
    const float* bv = (const float*)d_in[9];
    const float* Wo = (const float*)d_in[10];
    const float* bo = (const float*)d_in[11];
    const float* ln1_g = (const float*)d_in[12];
    const float* ln1_b = (const float*)d_in[13];
    const float* ln2_g = (const float*)d_in[14];
    const float* ln2_b = (const float*)d_in[15];
    const float* W1 = (const float*)d_in[16];
    const float* b1 = (const float*)d_in[17];
    const float* W2 = (const float*)d_in[18];
    const float* b2 = (const float*)d_in[19];
    float* out = (float*)d_out;

    const size_t S = (size_t)ROWS * D_MODEL;
    float* ws  = (float*)d_ws;
    float* h   = ws;
    float* Qm  = ws + S;
    float* Km  = ws + 2 * S;
    float* Vm  = ws + 3 * S;
    float* ao  = ws + 4 * S;
    float* x2  = ws + 5 * S;
    float* mid = ws + 6 * S;

    ln_kernel<<<ROWS, 256, 0, stream>>>(x, ln1_g, ln1_b, h);
    dim3 g768(D_MODEL / 128, ROWS / 128);
    gemm_kernel<0, false><<<g768, 256, 0, stream>>>(h, Wq, bq, nullptr, Qm, ROWS, D_MODEL, D_MODEL);
    gemm_kernel<0, false><<<g768, 256, 0, stream>>>(h, Wk, bk, nullptr, Km, ROWS, D_MODEL, D_MODEL);
    gemm_kernel<0, false><<<g768, 256, 0, stream>>>(h, Wv, bv, nullptr, Vm, ROWS, D_MODEL, D_MODEL);
    attn_mfma_kernel<<<dim3(32, BATCH * N_HEADS), 128, 0, stream>>>(Qm, Km, Vm, q_pos, k_pos, ao);
    gemm_kernel<0, true><<<g768, 256, 0, stream>>>(ao, Wo, bo, x, x2, ROWS, D_MODEL, D_MODEL);
    ln_kernel<<<ROWS, 256, 0, stream>>>(x2, ln2_g, ln2_b, h);
    dim3 g3072(D_FFN / 128, ROWS / 128);
    gemm_kernel<1, false><<<g3072, 256, 0, stream>>>(h, W1, b1, nullptr, mid, ROWS, D_FFN, D_MODEL);
    gemm_kernel<0, true><<<g768, 256, 0, stream>>>(mid, W2, b2, x2, out, ROWS, D_MODEL, D_FFN);
}

// Round 3
// 353.955 us; speedup vs baseline: 18.0554x; 3.6035x over previous
//
#include <hip/hip_runtime.h>
#include <hip/hip_bf16.h>
#include <math.h>

#define D_MODEL 768
#define N_HEADS 12
#define D_HEAD  64
#define BATCH   2
#define SEQ     2048
#define ROWS    (BATCH*SEQ)          // 4096
#define D_FFN   (4*D_MODEL)          // 3072

typedef short bf16x8 __attribute__((ext_vector_type(8)));
typedef float f32x4  __attribute__((ext_vector_type(4)));

__device__ __forceinline__ short f2bf(float f) {
    __hip_bfloat16 h = __float2bfloat16(f);
    return *reinterpret_cast<short*>(&h);
}

// ---------------------------------------------------------------- converts
__global__ __launch_bounds__(256)
void convert_bf16_kernel(const float* __restrict__ in, short* __restrict__ out) {
    int i = (blockIdx.x * 256 + threadIdx.x) * 8;
    float4 a = *reinterpret_cast<const float4*>(in + i);
    float4 b = *reinterpret_cast<const float4*>(in + i + 4);
    bf16x8 r;
    r[0]=f2bf(a.x); r[1]=f2bf(a.y); r[2]=f2bf(a.z); r[3]=f2bf(a.w);
    r[4]=f2bf(b.x); r[5]=f2bf(b.y); r[6]=f2bf(b.z); r[7]=f2bf(b.w);
    *reinterpret_cast<bf16x8*>(out + i) = r;
}

// W[K][N] fp32 -> WT[N][K] bf16 (tiled transpose)
__global__ __launch_bounds__(256)
void transpose_bf16_kernel(const float* __restrict__ W, short* __restrict__ WT,
                           int K, int N) {
    __shared__ float tile[32][33];
    int n0 = blockIdx.x * 32, k0 = blockIdx.y * 32;
    int tx = threadIdx.x & 31, ty = threadIdx.x >> 5;   // 32 x 8
    #pragma unroll
    for (int i = 0; i < 4; ++i)
        tile[ty + 8*i][tx] = W[(size_t)(k0 + ty + 8*i) * N + n0 + tx];
    __syncthreads();
    #pragma unroll
    for (int i = 0; i < 4; ++i)
        WT[(size_t)(n0 + ty + 8*i) * K + k0 + tx] = f2bf(tile[tx][ty + 8*i]);
}

// ---------------------------------------------------------------- LayerNorm (fp32 in -> bf16 out)
__global__ __launch_bounds__(256)
void ln_kernel(const float* __restrict__ x, const float* __restrict__ g,
               const float* __restrict__ beta, short* __restrict__ out) {
    int row = blockIdx.x;
    const float* xr = x + (size_t)row * D_MODEL;
    int t = threadIdx.x;
    float v0 = xr[t], v1 = xr[t + 256], v2 = xr[t + 512];
    float s  = v0 + v1 + v2;
    float s2 = v0*v0 + v1*v1 + v2*v2;
    __shared__ float rs[4], rs2[4];
    #pragma unroll
    for (int off = 32; off; off >>= 1) {
        s  += __shfl_down(s, off);
        s2 += __shfl_down(s2, off);
    }
    int wv = t >> 6, ln = t & 63;
    if (ln == 0) { rs[wv] = s; rs2[wv] = s2; }
    __syncthreads();
    float S  = rs[0] + rs[1] + rs[2] + rs[3];
    float S2 = rs2[0] + rs2[1] + rs2[2] + rs2[3];
    float mu  = S * (1.0f / D_MODEL);
    float var = S2 * (1.0f / D_MODEL) - mu * mu;
    float inv = rsqrtf(var + 1e-5f);
    short* orow = out + (size_t)row * D_MODEL;
    orow[t]       = f2bf((v0 - mu) * inv * g[t]       + beta[t]);
    orow[t + 256] = f2bf((v1 - mu) * inv * g[t + 256] + beta[t + 256]);
    orow[t + 512] = f2bf((v2 - mu) * inv * g[t + 512] + beta[t + 512]);
}

// ---------------------------------------------------------------- bf16 MFMA GEMM (m97 structure)
// C[M,N] = A[M,K] @ WT[N,K]^T + bias [+res]; ACT=1 -> exact GELU. 128x128 tile,
// BK=32, 256 thr = 4 waves (2x2), 4x4 16x16 frags/wave, global_load_lds staging.
template<int ACT, bool RES, bool OUTBF>
__device__ __forceinline__
void gemm_body(const short* __restrict__ A, const short* __restrict__ WT,
               const float* __restrict__ bias, const float* __restrict__ res,
               void* __restrict__ Cout, int M, int N, int K) {
    __shared__ short As[128 * 32];
    __shared__ short Bs[128 * 32];
    const int tid = threadIdx.x;
    const int w = tid >> 6, lane = tid & 63;
    const int lr = lane & 15, lg = lane >> 4;
    const int wm = w >> 1, wn = w & 1;
    const int bm = blockIdx.y * 128, bn = blockIdx.x * 128;

    f32x4 acc[4][4] = {};

    // wave w stages rows [w*32, w*32+32) of both tiles
    const int srow = w * 32 + (lane >> 2);          // + r*16
    const int scol = (lane & 3) * 8;
    const short* Ag = A  + (size_t)(bm + srow) * K + scol;
    const short* Bg = WT + (size_t)(bn + srow) * K + scol;

    for (int k0 = 0; k0 < K; k0 += 32) {
        __syncthreads();
        #pragma unroll
        for (int r = 0; r < 2; ++r) {
            __builtin_amdgcn_global_load_lds(
                (const __attribute__((address_space(1))) void*)(Ag + (size_t)r * 16 * K + k0),
                (__attribute__((address_space(3))) void*)(As + w * 1024 + r * 512),
                16, 0, 0);
            __builtin_amdgcn_global_load_lds(
                (const __attribute__((address_space(1))) void*)(Bg + (size_t)r * 16 * K + k0),
                (__attribute__((address_space(3))) void*)(Bs + w * 1024 + r * 512),
                16, 0, 0);
        }
        __syncthreads();
        bf16x8 af[4], bfr[4];
        #pragma unroll
        for (int mi = 0; mi < 4; ++mi)
            af[mi] = *reinterpret_cast<const bf16x8*>(As + (wm*64 + mi*16 + lr) * 32 + lg*8);
        #pragma unroll
        for (int nj = 0; nj < 4; ++nj)
            bfr[nj] = *reinterpret_cast<const bf16x8*>(Bs + (wn*64 + nj*16 + lr) * 32 + lg*8);
        #pragma unroll
        for (int mi = 0; mi < 4; ++mi)
            #pragma unroll
            for (int nj = 0; nj < 4; ++nj)
                acc[mi][nj] = __builtin_amdgcn_mfma_f32_16x16x32_bf16(af[mi], bfr[nj], acc[mi][nj], 0, 0, 0);
    }

    float bias_v[4];
    #pragma unroll
    for (int nj = 0; nj < 4; ++nj) bias_v[nj] = bias[bn + wn*64 + nj*16 + lr];

    #pragma unroll
    for (int mi = 0; mi < 4; ++mi) {
        #pragma unroll
        for (int j = 0; j < 4; ++j) {
            size_t m = bm + wm*64 + mi*16 + lg*4 + j;
            #pragma unroll
            for (int nj = 0; nj < 4; ++nj) {
                size_t n = bn + wn*64 + nj*16 + lr;
                float v = acc[mi][nj][j] + bias_v[nj];
                if (RES) v += res[m * N + n];
                if (ACT == 1) v = 0.5f * v * (1.0f + erff(v * 0.70710678118f));
                if (OUTBF) ((short*)Cout)[m * N + n] = f2bf(v);
                else       ((float*)Cout)[m * N + n] = v;
            }
        }
    }
}

template<int ACT, bool RES, bool OUTBF>
__global__ __launch_bounds__(256)
void gemm_mfma_kernel(const short* __restrict__ A, const short* __restrict__ WT,
                      const float* __restrict__ bias, const float* __restrict__ res,
                      void* __restrict__ Cout, int M, int N, int K) {
    gemm_body<ACT, RES, OUTBF>(A, WT, bias, res, Cout, M, N, K);
}

__global__ __launch_bounds__(256)
void gemm_qkv_kernel(const short* __restrict__ A,
                     const short* __restrict__ WTq, const short* __restrict__ WTk,
                     const short* __restrict__ WTv,
                     const float* __restrict__ bq, const float* __restrict__ bk,
                     const float* __restrict__ bv,
                     short* __restrict__ Qm, short* __restrict__ Km, short* __restrict__ Vm) {
    const short* WT; const float* bias; short* C;
    if (blockIdx.z == 0)      { WT = WTq; bias = bq; C = Qm; }
    else if (blockIdx.z == 1) { WT = WTk; bias = bk; C = Km; }
    else                      { WT = WTv; bias = bv; C = Vm; }
    gemm_body<0, false, true>(A, WT, bias, nullptr, C, ROWS, D_MODEL, D_MODEL);
}

// ---------------------------------------------------------------- MFMA flash attention (bf16 in/out)
__global__ __launch_bounds__(128)
void attn_mfma_kernel(const short* __restrict__ Q, const short* __restrict__ K,
                      const short* __restrict__ V, const short* __restrict__ qp,
                      const short* __restrict__ kp, short* __restrict__ ao) {
    int pairIdx = blockIdx.x;            // 0..31
    int bh = blockIdx.y;                 // b*12+h
    int b = bh / N_HEADS, h = bh % N_HEADS;
    __shared__ short Vt[64][72];
    __shared__ short Plds[2][16][72];
    int tid  = threadIdx.x;
    int w    = tid >> 6, lane = tid & 63;
    int lr   = lane & 15;
    int lg   = lane >> 4;

    #pragma unroll
    for (int phase = 0; phase < 2; ++phase) {
        int qt    = (phase == 0) ? pairIdx : 63 - pairIdx;
        int qbase = qt * 32 + w * 16;

        const short* Qrow  = Q  + ((size_t)(b * SEQ) + qbase + lr) * D_MODEL + h * 64;
        const short* qprow = qp + ((size_t)bh * SEQ + qbase + lr) * 64;
        bf16x8 qf0  = *reinterpret_cast<const bf16x8*>(Qrow  + lg * 8);
        bf16x8 qf1  = *reinterpret_cast<const bf16x8*>(Qrow  + 32 + lg * 8);
        bf16x8 qpf0 = *reinterpret_cast<const bf16x8*>(qprow + lg * 8);
        bf16x8 qpf1 = *reinterpret_cast<const bf16x8*>(qprow + 32 + lg * 8);

        f32x4 o_acc[4] = {};
        float m_run[4], l_run[4];
        #pragma unroll
        for (int r = 0; r < 4; ++r) { m_run[r] = -1e30f; l_run[r] = 0.f; }

        int nkt = qt / 2 + 1;
        for (int kt = 0; kt < nkt; ++kt) {
            __syncthreads();
            {   // stage V^T
                int row = tid & 63, cb = (tid >> 6) * 32;
                const short* vr = V + ((size_t)(b * SEQ) + kt * 64 + row) * D_MODEL + h * 64 + cb;
                #pragma unroll
                for (int c8 = 0; c8 < 4; ++c8) {
                    bf16x8 v = *reinterpret_cast<const bf16x8*>(vr + c8 * 8);
                    #pragma unroll
                    for (int e = 0; e < 8; ++e) Vt[cb + c8*8 + e][row] = v[e];
                }
            }
            __syncthreads();

            f32x4 sx[4] = {}, sp[4] = {};
            const short* Kbase  = K  + ((size_t)(b * SEQ) + kt * 64) * D_MODEL + h * 64;
            const short* kpbase = kp + ((size_t)bh * SEQ + kt * 64) * 64;
            #pragma unroll
            for (int sub = 0; sub < 4; ++sub) {
                const short* kr  = Kbase  + (size_t)(sub * 16 + lr) * D_MODEL;
                const short* kpr = kpbase + (size_t)(sub * 16 + lr) * 64;
                bf16x8 kf0 = *reinterpret_cast<const bf16x8*>(kr  + lg * 8);
                bf16x8 kf1 = *reinterpret_cast<const bf16x8*>(kr  + 32 + lg * 8);
                bf16x8 kq0 = *reinterpret_cast<const bf16x8*>(kpr + lg * 8);
                bf16x8 kq1 = *reinterpret_cast<const bf16x8*>(kpr + 32 + lg * 8);
                sx[sub] = __builtin_amdgcn_mfma_f32_16x16x32_bf16(qf0,  kf0, sx[sub], 0, 0, 0);
                sx[sub] = __builtin_amdgcn_mfma_f32_16x16x32_bf16(qf1,  kf1, sx[sub], 0, 0, 0);
                sp[sub] = __builtin_amdgcn_mfma_f32_16x16x32_bf16(qpf0, kq0, sp[sub], 0, 0, 0);
                sp[sub] = __builtin_amdgcn_mfma_f32_16x16x32_bf16(qpf1, kq1, sp[sub], 0, 0, 0);
            }

            float sc[4][4];
            float pmax[4];
            #pragma unroll
            for (int r = 0; r < 4; ++r) {
                int row = qbase + lg * 4 + r;
                float mx = -1e30f;
                #pragma unroll
                for (int sub = 0; sub < 4; ++sub) {
                    int col = kt * 64 + sub * 16 + lr;
                    float v = sx[sub][r] * sp[sub][r] * (1.0f / 64.0f);
                    if (col > row) v = -1e30f;
                    sc[sub][r] = v;
                    mx = fmaxf(mx, v);
                }
                pmax[r] = mx;
            }
            #pragma unroll
            for (int off = 1; off < 16; off <<= 1)
                #pragma unroll
                for (int r = 0; r < 4; ++r)
                    pmax[r] = fmaxf(pmax[r], __shfl_xor(pmax[r], off));

            float psum[4];
            #pragma unroll
            for (int r = 0; r < 4; ++r) {
                float m_new = fmaxf(m_run[r], pmax[r]);
                float scale = __expf(m_run[r] - m_new);
                m_run[r] = m_new;
                float s = 0.f;
                #pragma unroll
                for (int sub = 0; sub < 4; ++sub) {
                    float p = __expf(sc[sub][r] - m_new);
                    sc[sub][r] = p;
                    s += p;
                }
                psum[r] = s;
                l_run[r] *= scale;
                #pragma unroll
                for (int ds = 0; ds < 4; ++ds) o_acc[ds][r] *= scale;
            }
            #pragma unroll
            for (int off = 1; off < 16; off <<= 1)
                #pragma unroll
                for (int r = 0; r < 4; ++r)
                    psum[r] += __shfl_xor(psum[r], off);
            #pragma unroll
            for (int r = 0; r < 4; ++r) l_run[r] += psum[r];

            #pragma unroll
            for (int sub = 0; sub < 4; ++sub)
                #pragma unroll
                for (int r = 0; r < 4; ++r)
                    Plds[w][lg * 4 + r][sub * 16 + lr] = f2bf(sc[sub][r]);

            bf16x8 pa0 = *reinterpret_cast<bf16x8*>(&Plds[w][lr][lg * 8]);
            bf16x8 pa1 = *reinterpret_cast<bf16x8*>(&Plds[w][lr][32 + lg * 8]);

            #pragma unroll
            for (int ds = 0; ds < 4; ++ds) {
                bf16x8 vb0 = *reinterpret_cast<bf16x8*>(&Vt[ds * 16 + lr][lg * 8]);
                bf16x8 vb1 = *reinterpret_cast<bf16x8*>(&Vt[ds * 16 + lr][32 + lg * 8]);
                o_acc[ds] = __builtin_amdgcn_mfma_f32_16x16x32_bf16(pa0, vb0, o_acc[ds], 0, 0, 0);
                o_acc[ds] = __builtin_amdgcn_mfma_f32_16x16x32_bf16(pa1, vb1, o_acc[ds], 0, 0, 0);
            }
        }

        #pragma unroll
        for (int ds = 0; ds < 4; ++ds)
            #pragma unroll
            for (int r = 0; r < 4; ++r) {
                int row = qbase + lg * 4 + r;
                float val = o_acc[ds][r] / l_run[r];
                ao[((size_t)(b * SEQ) + row) * D_MODEL + h * 64 + ds * 16 + lr] = f2bf(val);
            }
        __syncthreads();
    }
}

// ---------------------------------------------------------------- launch
extern "C" void kernel_launch(void* const* d_in, const int* in_sizes, int n_in,
                              void* d_out, int out_size, void* d_ws, size_t ws_size,
                              hipStream_t stream) {
    const float* x     = (const float*)d_in[0];
    const float* q_pos = (const float*)d_in[1];
    const float* k_pos = (const float*)d_in[2];
    const float* Wq = (const float*)d_in[4];
    const float* bq = (const float*)d_in[5];
    const float* Wk = (const float*)d_in[6];
    const float* bk = (const float*)d_in[7];
    const float* Wv = (const float*)d_in[8];
    const float* bv = (const float*)d_in[9];
    const float* Wo = (const float*)d_in[10];
    const float* bo = (const float*)d_in[11];
    const float* ln1_g = (const float*)d_in[12];
    const float* ln1_b = (const float*)d_in[13];
    const float* ln2_g = (const float*)d_in[14];
    const float* ln2_b = (const float*)d_in[15];
    const float* W1 = (const float*)d_in[16];
    const float* b1 = (const float*)d_in[17];
    const float* W2 = (const float*)d_in[18];
    const float* b2 = (const float*)d_in[19];
    float* out = (float*)d_out;

    char* p = (char*)d_ws;
    auto alloc = [&](size_t bytes) { char* q = p; p += (bytes + 255) & ~(size_t)255; return q; };
    const size_t SA = (size_t)ROWS * D_MODEL;      // 3145728 elems
    const size_t SP = (size_t)BATCH * N_HEADS * SEQ * 64;  // 3145728 elems

    short* h_bf  = (short*)alloc(SA * 2);
    short* Qm    = (short*)alloc(SA * 2);
    short* Km    = (short*)alloc(SA * 2);
    short* Vm    = (short*)alloc(SA * 2);
    short* ao    = (short*)alloc(SA * 2);
    short* qp_bf = (short*)alloc(SP * 2);
    short* kp_bf = (short*)alloc(SP * 2);
    short* mid   = (short*)alloc((size_t)ROWS * D_FFN * 2);
    float* x2    = (float*)alloc(SA * 4);
    short* WTq   = (short*)alloc((size_t)D_MODEL * D_MODEL * 2);
    short* WTk   = (short*)alloc((size_t)D_MODEL * D_MODEL * 2);
    short* WTv   = (short*)alloc((size_t)D_MODEL * D_MODEL * 2);
    short* WTo   = (short*)alloc((size_t)D_MODEL * D_MODEL * 2);
    short* WT1   = (short*)alloc((size_t)D_MODEL * D_FFN * 2);
    short* WT2   = (short*)alloc((size_t)D_MODEL * D_FFN * 2);

    // weight prep
    dim3 t768(24, 24), t1(96, 24), t2(24, 96);
    transpose_bf16_kernel<<<t768, 256, 0, stream>>>(Wq, WTq, D_MODEL, D_MODEL);
    transpose_bf16_kernel<<<t768, 256, 0, stream>>>(Wk, WTk, D_MODEL, D_MODEL);
    transpose_bf16_kernel<<<t768, 256, 0, stream>>>(Wv, WTv, D_MODEL, D_MODEL);
    transpose_bf16_kernel<<<t768, 256, 0, stream>>>(Wo, WTo, D_MODEL, D_MODEL);
    transpose_bf16_kernel<<<t1,   256, 0, stream>>>(W1, WT1, D_MODEL, D_FFN);
    transpose_bf16_kernel<<<t2,   256, 0, stream>>>(W2, WT2, D_FFN, D_MODEL);
    convert_bf16_kernel<<<SP / 2048, 256, 0, stream>>>(q_pos, qp_bf);
    convert_bf16_kernel<<<SP / 2048, 256, 0, stream>>>(k_pos, kp_bf);

    // layer
    ln_kernel<<<ROWS, 256, 0, stream>>>(x, ln1_g, ln1_b, h_bf);
    gemm_qkv_kernel<<<dim3(D_MODEL/128, ROWS/128, 3), 256, 0, stream>>>(
        h_bf, WTq, WTk, WTv, bq, bk, bv, Qm, Km, Vm);
    attn_mfma_kernel<<<dim3(32, BATCH * N_HEADS), 128, 0, stream>>>(Qm, Km, Vm, qp_bf, kp_bf, ao);
    gemm_mfma_kernel<0, true, false><<<dim3(D_MODEL/128, ROWS/128), 256, 0, stream>>>(
        ao, WTo, bo, x, x2, ROWS, D_MODEL, D_MODEL);
    ln_kernel<<<ROWS, 256, 0, stream>>>(x2, ln2_g, ln2_b, h_bf);
    gemm_mfma_kernel<1, false, true><<<dim3(D_FFN/128, ROWS/128), 256, 0, stream>>>(
        h_bf, WT1, b1, nullptr, mid, ROWS, D_FFN, D_MODEL);
    gemm_mfma_kernel<0, true, false><<<dim3(D_MODEL/128, ROWS/128), 256, 0, stream>>>(
        mid, WT2, b2, x2, out, ROWS, D_MODEL, D_FFN);
}

// Round 4
// 336.216 us; speedup vs baseline: 19.0080x; 1.0528x over previous
//
#include <hip/hip_runtime.h>
#include <hip/hip_bf16.h>
#include <math.h>

#define D_MODEL 768
#define N_HEADS 12
#define D_HEAD  64
#define BATCH   2
#define SEQ     2048
#define ROWS    (BATCH*SEQ)          // 4096
#define D_FFN   (4*D_MODEL)          // 3072

typedef short bf16x8 __attribute__((ext_vector_type(8)));
typedef float f32x4  __attribute__((ext_vector_type(4)));

__device__ __forceinline__ short f2bf(float f) {
    __hip_bfloat16 h = __float2bfloat16(f);
    return *reinterpret_cast<short*>(&h);
}

// ---------------------------------------------------------------- converts
__global__ __launch_bounds__(256)
void convert_bf16_kernel(const float* __restrict__ in, short* __restrict__ out) {
    int i = (blockIdx.x * 256 + threadIdx.x) * 8;
    float4 a = *reinterpret_cast<const float4*>(in + i);
    float4 b = *reinterpret_cast<const float4*>(in + i + 4);
    bf16x8 r;
    r[0]=f2bf(a.x); r[1]=f2bf(a.y); r[2]=f2bf(a.z); r[3]=f2bf(a.w);
    r[4]=f2bf(b.x); r[5]=f2bf(b.y); r[6]=f2bf(b.z); r[7]=f2bf(b.w);
    *reinterpret_cast<bf16x8*>(out + i) = r;
}

// W[K][N] fp32 -> WT[N][K] bf16 (tiled transpose)
__global__ __launch_bounds__(256)
void transpose_bf16_kernel(const float* __restrict__ W, short* __restrict__ WT,
                           int K, int N) {
    __shared__ float tile[32][33];
    int n0 = blockIdx.x * 32, k0 = blockIdx.y * 32;
    int tx = threadIdx.x & 31, ty = threadIdx.x >> 5;   // 32 x 8
    #pragma unroll
    for (int i = 0; i < 4; ++i)
        tile[ty + 8*i][tx] = W[(size_t)(k0 + ty + 8*i) * N + n0 + tx];
    __syncthreads();
    #pragma unroll
    for (int i = 0; i < 4; ++i)
        WT[(size_t)(n0 + ty + 8*i) * K + k0 + tx] = f2bf(tile[tx][ty + 8*i]);
}

// Vm [ROWS][768] bf16 -> Vt [24][64][2048] bf16 (per-head V^T)
__global__ __launch_bounds__(256)
void transpose_v_kernel(const short* __restrict__ Vm, short* __restrict__ Vt) {
    __shared__ short tile[64][72];
    int kt = blockIdx.x;        // 32 k-tiles of 64
    int bh = blockIdx.y;        // 24
    int b = bh / N_HEADS, h = bh % N_HEADS;
    int tid = threadIdx.x;
    int row = tid >> 2, c16 = (tid & 3) * 16;
    const short* src = Vm + ((size_t)(b * SEQ) + kt * 64 + row) * D_MODEL + h * 64 + c16;
    *reinterpret_cast<bf16x8*>(&tile[row][c16])     = *reinterpret_cast<const bf16x8*>(src);
    *reinterpret_cast<bf16x8*>(&tile[row][c16 + 8]) = *reinterpret_cast<const bf16x8*>(src + 8);
    __syncthreads();
    int d = tid >> 2, k16 = (tid & 3) * 16;
    short o[16];
    #pragma unroll
    for (int j = 0; j < 16; ++j) o[j] = tile[k16 + j][d];
    short* dst = Vt + ((size_t)bh * 64 + d) * SEQ + kt * 64 + k16;
    *reinterpret_cast<bf16x8*>(dst)     = *reinterpret_cast<bf16x8*>(&o[0]);
    *reinterpret_cast<bf16x8*>(dst + 8) = *reinterpret_cast<bf16x8*>(&o[8]);
}

// ---------------------------------------------------------------- LayerNorm (fp32 in -> bf16 out)
__global__ __launch_bounds__(256)
void ln_kernel(const float* __restrict__ x, const float* __restrict__ g,
               const float* __restrict__ beta, short* __restrict__ out) {
    int row = blockIdx.x;
    const float* xr = x + (size_t)row * D_MODEL;
    int t = threadIdx.x;
    float v0 = xr[t], v1 = xr[t + 256], v2 = xr[t + 512];
    float s  = v0 + v1 + v2;
    float s2 = v0*v0 + v1*v1 + v2*v2;
    __shared__ float rs[4], rs2[4];
    #pragma unroll
    for (int off = 32; off; off >>= 1) {
        s  += __shfl_down(s, off);
        s2 += __shfl_down(s2, off);
    }
    int wv = t >> 6, ln = t & 63;
    if (ln == 0) { rs[wv] = s; rs2[wv] = s2; }
    __syncthreads();
    float S  = rs[0] + rs[1] + rs[2] + rs[3];
    float S2 = rs2[0] + rs2[1] + rs2[2] + rs2[3];
    float mu  = S * (1.0f / D_MODEL);
    float var = S2 * (1.0f / D_MODEL) - mu * mu;
    float inv = rsqrtf(var + 1e-5f);
    short* orow = out + (size_t)row * D_MODEL;
    orow[t]       = f2bf((v0 - mu) * inv * g[t]       + beta[t]);
    orow[t + 256] = f2bf((v1 - mu) * inv * g[t + 256] + beta[t + 256]);
    orow[t + 512] = f2bf((v2 - mu) * inv * g[t + 512] + beta[t + 512]);
}

// ---------------------------------------------------------------- bf16 MFMA GEMM (m97 structure)
template<int ACT, bool RES, bool OUTBF>
__device__ __forceinline__
void gemm_body(const short* __restrict__ A, const short* __restrict__ WT,
               const float* __restrict__ bias, const float* __restrict__ res,
               void* __restrict__ Cout, int M, int N, int K) {
    __shared__ short As[128 * 32];
    __shared__ short Bs[128 * 32];
    const int tid = threadIdx.x;
    const int w = tid >> 6, lane = tid & 63;
    const int lr = lane & 15, lg = lane >> 4;
    const int wm = w >> 1, wn = w & 1;
    const int bm = blockIdx.y * 128, bn = blockIdx.x * 128;

    f32x4 acc[4][4] = {};

    const int srow = w * 32 + (lane >> 2);
    const int scol = (lane & 3) * 8;
    const short* Ag = A  + (size_t)(bm + srow) * K + scol;
    const short* Bg = WT + (size_t)(bn + srow) * K + scol;

    for (int k0 = 0; k0 < K; k0 += 32) {
        __syncthreads();
        #pragma unroll
        for (int r = 0; r < 2; ++r) {
            __builtin_amdgcn_global_load_lds(
                (const __attribute__((address_space(1))) void*)(Ag + (size_t)r * 16 * K + k0),
                (__attribute__((address_space(3))) void*)(As + w * 1024 + r * 512),
                16, 0, 0);
            __builtin_amdgcn_global_load_lds(
                (const __attribute__((address_space(1))) void*)(Bg + (size_t)r * 16 * K + k0),
                (__attribute__((address_space(3))) void*)(Bs + w * 1024 + r * 512),
                16, 0, 0);
        }
        __syncthreads();
        bf16x8 af[4], bfr[4];
        #pragma unroll
        for (int mi = 0; mi < 4; ++mi)
            af[mi] = *reinterpret_cast<const bf16x8*>(As + (wm*64 + mi*16 + lr) * 32 + lg*8);
        #pragma unroll
        for (int nj = 0; nj < 4; ++nj)
            bfr[nj] = *reinterpret_cast<const bf16x8*>(Bs + (wn*64 + nj*16 + lr) * 32 + lg*8);
        #pragma unroll
        for (int mi = 0; mi < 4; ++mi)
            #pragma unroll
            for (int nj = 0; nj < 4; ++nj)
                acc[mi][nj] = __builtin_amdgcn_mfma_f32_16x16x32_bf16(af[mi], bfr[nj], acc[mi][nj], 0, 0, 0);
    }

    float bias_v[4];
    #pragma unroll
    for (int nj = 0; nj < 4; ++nj) bias_v[nj] = bias[bn + wn*64 + nj*16 + lr];

    #pragma unroll
    for (int mi = 0; mi < 4; ++mi) {
        #pragma unroll
        for (int j = 0; j < 4; ++j) {
            size_t m = bm + wm*64 + mi*16 + lg*4 + j;
            #pragma unroll
            for (int nj = 0; nj < 4; ++nj) {
                size_t n = bn + wn*64 + nj*16 + lr;
                float v = acc[mi][nj][j] + bias_v[nj];
                if (RES) v += res[m * N + n];
                if (ACT == 1) v = 0.5f * v * (1.0f + erff(v * 0.70710678118f));
                if (OUTBF) ((short*)Cout)[m * N + n] = f2bf(v);
                else       ((float*)Cout)[m * N + n] = v;
            }
        }
    }
}

template<int ACT, bool RES, bool OUTBF>
__global__ __launch_bounds__(256)
void gemm_mfma_kernel(const short* __restrict__ A, const short* __restrict__ WT,
                      const float* __restrict__ bias, const float* __restrict__ res,
                      void* __restrict__ Cout, int M, int N, int K) {
    gemm_body<ACT, RES, OUTBF>(A, WT, bias, res, Cout, M, N, K);
}

__global__ __launch_bounds__(256)
void gemm_qkv_kernel(const short* __restrict__ A,
                     const short* __restrict__ WTq, const short* __restrict__ WTk,
                     const short* __restrict__ WTv,
                     const float* __restrict__ bq, const float* __restrict__ bk,
                     const float* __restrict__ bv,
                     short* __restrict__ Qm, short* __restrict__ Km, short* __restrict__ Vm) {
    const short* WT; const float* bias; short* C;
    if (blockIdx.z == 0)      { WT = WTq; bias = bq; C = Qm; }
    else if (blockIdx.z == 1) { WT = WTk; bias = bk; C = Km; }
    else                      { WT = WTv; bias = bv; C = Vm; }
    gemm_body<0, false, true>(A, WT, bias, nullptr, C, ROWS, D_MODEL, D_MODEL);
}

// ---------------------------------------------------------------- MFMA flash attention v3
// 128 thr (2 waves), barrier-free. Block handles q-tiles pairIdx & 63-pairIdx
// (32 rows each; wave w owns 16). V read from pre-transposed Vt[bh][64][2048].
// K/kp frags register-prefetched one tile ahead; V frags issued before scores.
__global__ __launch_bounds__(128)
void attn_mfma_kernel(const short* __restrict__ Q, const short* __restrict__ K,
                      const short* __restrict__ Vt, const short* __restrict__ qp,
                      const short* __restrict__ kp, short* __restrict__ ao) {
    int lin = blockIdx.y * 32 + blockIdx.x;          // 0..767
    int wid = (lin & 7) * 96 + (lin >> 3);           // bijective XCD swizzle (768=8*96)
    int pairIdx = wid & 31;
    int bh = wid >> 5;
    int b = bh / N_HEADS, h = bh % N_HEADS;
    __shared__ short Plds[2][16][72];
    int tid = threadIdx.x;
    int w = tid >> 6, lane = tid & 63;
    int lr = lane & 15, lg = lane >> 4;

    const short* Kh  = K  + ((size_t)(b * SEQ)) * D_MODEL + h * 64;
    const short* kph = kp + ((size_t)bh * SEQ) * 64;
    const short* Vth = Vt + ((size_t)bh * 64) * SEQ;

    #pragma unroll
    for (int phase = 0; phase < 2; ++phase) {
        int qt = phase ? 63 - pairIdx : pairIdx;
        int qbase = qt * 32 + w * 16;

        const short* Qrow  = Q  + ((size_t)(b * SEQ) + qbase + lr) * D_MODEL + h * 64;
        const short* qprow = qp + ((size_t)bh * SEQ + qbase + lr) * 64;
        bf16x8 qf0  = *reinterpret_cast<const bf16x8*>(Qrow + lg * 8);
        bf16x8 qf1  = *reinterpret_cast<const bf16x8*>(Qrow + 32 + lg * 8);
        bf16x8 qpf0 = *reinterpret_cast<const bf16x8*>(qprow + lg * 8);
        bf16x8 qpf1 = *reinterpret_cast<const bf16x8*>(qprow + 32 + lg * 8);

        f32x4 o_acc[4] = {};
        float m_run[4], l_run[4];
        #pragma unroll
        for (int r = 0; r < 4; ++r) { m_run[r] = -1e30f; l_run[r] = 0.f; }

        int nkt = qt / 2 + 1;

        bf16x8 kf[4][2], kq[4][2];
        #pragma unroll
        for (int sub = 0; sub < 4; ++sub) {         // tile 0
            const short* kr  = Kh  + (size_t)(sub * 16 + lr) * D_MODEL;
            const short* kpr = kph + (size_t)(sub * 16 + lr) * 64;
            kf[sub][0] = *reinterpret_cast<const bf16x8*>(kr + lg * 8);
            kf[sub][1] = *reinterpret_cast<const bf16x8*>(kr + 32 + lg * 8);
            kq[sub][0] = *reinterpret_cast<const bf16x8*>(kpr + lg * 8);
            kq[sub][1] = *reinterpret_cast<const bf16x8*>(kpr + 32 + lg * 8);
        }

        for (int kt = 0; kt < nkt; ++kt) {
            // V frags for this tile — issue early, consumed only in PV
            bf16x8 vb[4][2];
            #pragma unroll
            for (int ds = 0; ds < 4; ++ds) {
                const short* vr = Vth + (size_t)(ds * 16 + lr) * SEQ + kt * 64;
                vb[ds][0] = *reinterpret_cast<const bf16x8*>(vr + lg * 8);
                vb[ds][1] = *reinterpret_cast<const bf16x8*>(vr + 32 + lg * 8);
            }

            f32x4 sx[4] = {}, sp[4] = {};
            __builtin_amdgcn_s_setprio(1);
            #pragma unroll
            for (int sub = 0; sub < 4; ++sub) {
                sx[sub] = __builtin_amdgcn_mfma_f32_16x16x32_bf16(qf0,  kf[sub][0], sx[sub], 0, 0, 0);
                sx[sub] = __builtin_amdgcn_mfma_f32_16x16x32_bf16(qf1,  kf[sub][1], sx[sub], 0, 0, 0);
                sp[sub] = __builtin_amdgcn_mfma_f32_16x16x32_bf16(qpf0, kq[sub][0], sp[sub], 0, 0, 0);
                sp[sub] = __builtin_amdgcn_mfma_f32_16x16x32_bf16(qpf1, kq[sub][1], sp[sub], 0, 0, 0);
            }
            __builtin_amdgcn_s_setprio(0);

            // prefetch next K/kp tile into the (now consumed) registers
            if (kt + 1 < nkt) {
                #pragma unroll
                for (int sub = 0; sub < 4; ++sub) {
                    const short* kr  = Kh  + (size_t)((kt + 1) * 64 + sub * 16 + lr) * D_MODEL;
                    const short* kpr = kph + (size_t)((kt + 1) * 64 + sub * 16 + lr) * 64;
                    kf[sub][0] = *reinterpret_cast<const bf16x8*>(kr + lg * 8);
                    kf[sub][1] = *reinterpret_cast<const bf16x8*>(kr + 32 + lg * 8);
                    kq[sub][0] = *reinterpret_cast<const bf16x8*>(kpr + lg * 8);
                    kq[sub][1] = *reinterpret_cast<const bf16x8*>(kpr + 32 + lg * 8);
                }
            }

            // combine, mask, online softmax
            float sc[4][4];
            float pmax[4];
            #pragma unroll
            for (int r = 0; r < 4; ++r) {
                int row = qbase + lg * 4 + r;
                float mx = -1e30f;
                #pragma unroll
                for (int sub = 0; sub < 4; ++sub) {
                    int col = kt * 64 + sub * 16 + lr;
                    float v = sx[sub][r] * sp[sub][r] * (1.0f / 64.0f);
                    if (col > row) v = -1e30f;
                    sc[sub][r] = v;
                    mx = fmaxf(mx, v);
                }
                pmax[r] = mx;
            }
            #pragma unroll
            for (int off = 1; off < 16; off <<= 1)
                #pragma unroll
                for (int r = 0; r < 4; ++r)
                    pmax[r] = fmaxf(pmax[r], __shfl_xor(pmax[r], off));

            float psum[4];
            #pragma unroll
            for (int r = 0; r < 4; ++r) {
                float m_new = fmaxf(m_run[r], pmax[r]);
                float scale = __expf(m_run[r] - m_new);
                m_run[r] = m_new;
                float s = 0.f;
                #pragma unroll
                for (int sub = 0; sub < 4; ++sub) {
                    float p = __expf(sc[sub][r] - m_new);
                    sc[sub][r] = p;
                    s += p;
                }
                psum[r] = s;
                l_run[r] *= scale;
                #pragma unroll
                for (int ds = 0; ds < 4; ++ds) o_acc[ds][r] *= scale;
            }
            #pragma unroll
            for (int off = 1; off < 16; off <<= 1)
                #pragma unroll
                for (int r = 0; r < 4; ++r)
                    psum[r] += __shfl_xor(psum[r], off);
            #pragma unroll
            for (int r = 0; r < 4; ++r) l_run[r] += psum[r];

            // P -> bf16 -> per-wave LDS -> A-frags (no barrier: wave-private)
            #pragma unroll
            for (int sub = 0; sub < 4; ++sub)
                #pragma unroll
                for (int r = 0; r < 4; ++r)
                    Plds[w][lg * 4 + r][sub * 16 + lr] = f2bf(sc[sub][r]);

            bf16x8 pa0 = *reinterpret_cast<bf16x8*>(&Plds[w][lr][lg * 8]);
            bf16x8 pa1 = *reinterpret_cast<bf16x8*>(&Plds[w][lr][32 + lg * 8]);

            __builtin_amdgcn_s_setprio(1);
            #pragma unroll
            for (int ds = 0; ds < 4; ++ds) {
                o_acc[ds] = __builtin_amdgcn_mfma_f32_16x16x32_bf16(pa0, vb[ds][0], o_acc[ds], 0, 0, 0);
                o_acc[ds] = __builtin_amdgcn_mfma_f32_16x16x32_bf16(pa1, vb[ds][1], o_acc[ds], 0, 0, 0);
            }
            __builtin_amdgcn_s_setprio(0);
        }

        #pragma unroll
        for (int ds = 0; ds < 4; ++ds)
            #pragma unroll
            for (int r = 0; r < 4; ++r) {
                int row = qbase + lg * 4 + r;
                float val = o_acc[ds][r] / l_run[r];
                ao[((size_t)(b * SEQ) + row) * D_MODEL + h * 64 + ds * 16 + lr] = f2bf(val);
            }
    }
}

// ---------------------------------------------------------------- launch
extern "C" void kernel_launch(void* const* d_in, const int* in_sizes, int n_in,
                              void* d_out, int out_size, void* d_ws, size_t ws_size,
                              hipStream_t stream) {
    const float* x     = (const float*)d_in[0];
    const float* q_pos = (const float*)d_in[1];
    const float* k_pos = (const float*)d_in[2];
    const float* Wq = (const float*)d_in[4];
    const float* bq = (const float*)d_in[5];
    const float* Wk = (const float*)d_in[6];
    const float* bk = (const float*)d_in[7];
    const float* Wv = (const float*)d_in[8];
    const float* bv = (const float*)d_in[9];
    const float* Wo = (const float*)d_in[10];
    const float* bo = (const float*)d_in[11];
    const float* ln1_g = (const float*)d_in[12];
    const float* ln1_b = (const float*)d_in[13];
    const float* ln2_g = (const float*)d_in[14];
    const float* ln2_b = (const float*)d_in[15];
    const float* W1 = (const float*)d_in[16];
    const float* b1 = (const float*)d_in[17];
    const float* W2 = (const float*)d_in[18];
    const float* b2 = (const float*)d_in[19];
    float* out = (float*)d_out;

    char* p = (char*)d_ws;
    auto alloc = [&](size_t bytes) { char* q = p; p += (bytes + 255) & ~(size_t)255; return q; };
    const size_t SA = (size_t)ROWS * D_MODEL;
    const size_t SP = (size_t)BATCH * N_HEADS * SEQ * 64;

    short* h_bf  = (short*)alloc(SA * 2);
    short* Qm    = (short*)alloc(SA * 2);
    short* Km    = (short*)alloc(SA * 2);
    short* Vm    = (short*)alloc(SA * 2);
    short* Vt    = (short*)alloc(SP * 2);
    short* ao    = (short*)alloc(SA * 2);
    short* qp_bf = (short*)alloc(SP * 2);
    short* kp_bf = (short*)alloc(SP * 2);
    short* mid   = (short*)alloc((size_t)ROWS * D_FFN * 2);
    float* x2    = (float*)alloc(SA * 4);
    short* WTq   = (short*)alloc((size_t)D_MODEL * D_MODEL * 2);
    short* WTk   = (short*)alloc((size_t)D_MODEL * D_MODEL * 2);
    short* WTv   = (short*)alloc((size_t)D_MODEL * D_MODEL * 2);
    short* WTo   = (short*)alloc((size_t)D_MODEL * D_MODEL * 2);
    short* WT1   = (short*)alloc((size_t)D_MODEL * D_FFN * 2);
    short* WT2   = (short*)alloc((size_t)D_MODEL * D_FFN * 2);

    dim3 t768(24, 24), t1(96, 24), t2(24, 96);
    transpose_bf16_kernel<<<t768, 256, 0, stream>>>(Wq, WTq, D_MODEL, D_MODEL);
    transpose_bf16_kernel<<<t768, 256, 0, stream>>>(Wk, WTk, D_MODEL, D_MODEL);
    transpose_bf16_kernel<<<t768, 256, 0, stream>>>(Wv, WTv, D_MODEL, D_MODEL);
    transpose_bf16_kernel<<<t768, 256, 0, stream>>>(Wo, WTo, D_MODEL, D_MODEL);
    transpose_bf16_kernel<<<t1,   256, 0, stream>>>(W1, WT1, D_MODEL, D_FFN);
    transpose_bf16_kernel<<<t2,   256, 0, stream>>>(W2, WT2, D_FFN, D_MODEL);
    convert_bf16_kernel<<<SP / 2048, 256, 0, stream>>>(q_pos, qp_bf);
    convert_bf16_kernel<<<SP / 2048, 256, 0, stream>>>(k_pos, kp_bf);

    ln_kernel<<<ROWS, 256, 0, stream>>>(x, ln1_g, ln1_b, h_bf);
    gemm_qkv_kernel<<<dim3(D_MODEL/128, ROWS/128, 3), 256, 0, stream>>>(
        h_bf, WTq, WTk, WTv, bq, bk, bv, Qm, Km, Vm);
    transpose_v_kernel<<<dim3(SEQ/64, BATCH*N_HEADS), 256, 0, stream>>>(Vm, Vt);
    attn_mfma_kernel<<<dim3(32, BATCH * N_HEADS), 128, 0, stream>>>(Qm, Km, Vt, qp_bf, kp_bf, ao);
    gemm_mfma_kernel<0, true, false><<<dim3(D_MODEL/128, ROWS/128), 256, 0, stream>>>(
        ao, WTo, bo, x, x2, ROWS, D_MODEL, D_MODEL);
    ln_kernel<<<ROWS, 256, 0, stream>>>(x2, ln2_g, ln2_b, h_bf);
    gemm_mfma_kernel<1, false, true><<<dim3(D_FFN/128, ROWS/128), 256, 0, stream>>>(
        h_bf, WT1, b1, nullptr, mid, ROWS, D_FFN, D_MODEL);
    gemm_mfma_kernel<0, true, false><<<dim3(D_MODEL/128, ROWS/128), 256, 0, stream>>>(
        mid, WT2, b2, x2, out, ROWS, D_MODEL, D_FFN);
}